// Round 1
// baseline (1258.762 us; speedup 1.0000x reference)
//
#include <hip/hip_runtime.h>

#define VOCAB 32000
#define EMB 32
#define HID 16
#define SEQ 128
#define BATCH 32
#define NROW (SEQ * BATCH)  // 4096 rows = (t, b) pairs
#define R 16                // rows per block in logits kernel
#define T2 512              // threads in logits kernel

// Kernel 1: embedding gather + 128-step tanh recurrence.
// One block, 512 threads = 32 batch chains x 16 hidden units.
// Software-prefetch of X[t+1] (embedding rows) hides global latency behind
// the 48-FMA dot + tanh of step t. Writes H[t] to workspace.
__global__ __launch_bounds__(512) void rnn_recur(
    const int* __restrict__ idx, const float* __restrict__ lookup,
    const float* __restrict__ Wx, const float* __restrict__ Wh,
    float* __restrict__ Hout)
{
    __shared__ float sWx[EMB][HID];       // 512 f
    __shared__ float sWh[HID][HID];       // 256 f
    __shared__ float sH[BATCH][HID];      // 512 f
    __shared__ float sX[BATCH][EMB + 1];  // padded: breaks 4-way bank alias

    const int tid = threadIdx.x;
    const int b = tid >> 4, j = tid & 15;

    sWx[tid >> 4][tid & 15] = Wx[tid];            // tid spans EMB*HID = 512
    if (tid < HID * HID) sWh[tid >> 4][tid & 15] = Wh[tid];
    sH[b][j] = 1.0f;                              // torch inits H to ones

    // Each thread owns 2 consecutive floats of X[t]: (b, el), (b, el+1)
    const int el = (2 * tid) & 31;  // even
    float2 xr;
    {
        int row = idx[b];  // idx[t=0][b]
        xr = *(const float2*)(lookup + row * EMB + el);
    }
    __syncthreads();

    for (int t = 0; t < SEQ; ++t) {
        sX[b][el] = xr.x;
        sX[b][el + 1] = xr.y;
        __syncthreads();  // sX (and prev-iter sH) visible to all
        if (t + 1 < SEQ) {
            int row = idx[(t + 1) * BATCH + b];
            xr = *(const float2*)(lookup + row * EMB + el);  // prefetch t+1
        }
        float a0 = 0.f, a1 = 0.f, a2 = 0.f, a3 = 0.f;
        #pragma unroll
        for (int e = 0; e < EMB; e += 4) {
            a0 += sX[b][e + 0] * sWx[e + 0][j];
            a1 += sX[b][e + 1] * sWx[e + 1][j];
            a2 += sX[b][e + 2] * sWx[e + 2][j];
            a3 += sX[b][e + 3] * sWx[e + 3][j];
        }
        #pragma unroll
        for (int k = 0; k < HID; k += 4) {
            a0 += sH[b][k + 0] * sWh[k + 0][j];
            a1 += sH[b][k + 1] * sWh[k + 1][j];
            a2 += sH[b][k + 2] * sWh[k + 2][j];
            a3 += sH[b][k + 3] * sWh[k + 3][j];
        }
        float h = tanhf((a0 + a1) + (a2 + a3));
        __syncthreads();  // all reads of sH/sX complete before overwrite
        sH[b][j] = h;
        Hout[t * (BATCH * HID) + tid] = h;  // tid == b*HID + j
    }
}

// Kernel 2: logits + log_softmax, fused, two sweeps over vocab.
// Block handles R=16 rows (t,b). Sweep 1: s[r] = sum_v exp(logit). No max
// subtraction needed: |logit| <= sum_k |Wo[k][v]| ~ 8 (H is tanh-bounded),
// exp is safe in f32 and log_softmax is shift-invariant.
// Sweep 2: recompute logit (Wo is L2-resident), write logit - log(s).
__global__ __launch_bounds__(T2) void logits_lsm(
    const float* __restrict__ H, const float* __restrict__ Wo,
    float* __restrict__ out)
{
    __shared__ __align__(16) float sH[R][HID];
    __shared__ float sRed[T2][R + 1];  // +1 pad: conflict-free tree reduce
    __shared__ float sLogS[R];

    const int tid = threadIdx.x;
    const int row0 = blockIdx.x * R;

    if (tid < R * HID) sH[tid >> 4][tid & 15] = H[row0 * HID + tid];
    __syncthreads();

    float s[R];
    #pragma unroll
    for (int r = 0; r < R; ++r) s[r] = 0.f;

    // Sweep 1: sum of exp
    for (int v = 4 * tid; v < VOCAB; v += 4 * T2) {
        float4 wo[HID];
        #pragma unroll
        for (int k = 0; k < HID; ++k)
            wo[k] = *(const float4*)(Wo + (size_t)k * VOCAB + v);
        #pragma unroll
        for (int r = 0; r < R; ++r) {
            float l0 = 0, l1 = 0, l2 = 0, l3 = 0;
            #pragma unroll
            for (int k = 0; k < HID; ++k) {
                float h = sH[r][k];
                l0 += h * wo[k].x; l1 += h * wo[k].y;
                l2 += h * wo[k].z; l3 += h * wo[k].w;
            }
            s[r] += __expf(l0) + __expf(l1) + __expf(l2) + __expf(l3);
        }
    }

    // Block reduction of s[r] across T2 threads
    #pragma unroll
    for (int r = 0; r < R; ++r) sRed[tid][r] = s[r];
    __syncthreads();
    for (int off = T2 / 2; off > 0; off >>= 1) {
        if (tid < off) {
            #pragma unroll
            for (int r = 0; r < R; ++r) sRed[tid][r] += sRed[tid + off][r];
        }
        __syncthreads();
    }
    if (tid < R) sLogS[tid] = __logf(sRed[0][tid]);
    __syncthreads();

    float lgS[R];
    #pragma unroll
    for (int r = 0; r < R; ++r) lgS[r] = sLogS[r];

    // Sweep 2: recompute logits, subtract log-sum-exp, write out
    for (int v = 4 * tid; v < VOCAB; v += 4 * T2) {
        float4 wo[HID];
        #pragma unroll
        for (int k = 0; k < HID; ++k)
            wo[k] = *(const float4*)(Wo + (size_t)k * VOCAB + v);
        #pragma unroll
        for (int r = 0; r < R; ++r) {
            float l0 = 0, l1 = 0, l2 = 0, l3 = 0;
            #pragma unroll
            for (int k = 0; k < HID; ++k) {
                float h = sH[r][k];
                l0 += h * wo[k].x; l1 += h * wo[k].y;
                l2 += h * wo[k].z; l3 += h * wo[k].w;
            }
            float4 o;
            o.x = l0 - lgS[r]; o.y = l1 - lgS[r];
            o.z = l2 - lgS[r]; o.w = l3 - lgS[r];
            *(float4*)(out + (size_t)(row0 + r) * VOCAB + v) = o;
        }
    }
}

extern "C" void kernel_launch(void* const* d_in, const int* in_sizes, int n_in,
                              void* d_out, int out_size, void* d_ws, size_t ws_size,
                              hipStream_t stream) {
    const int*   idx    = (const int*)d_in[0];    // [SEQ, BATCH] int32
    const float* lookup = (const float*)d_in[1];  // [VOCAB, EMB]
    const float* Wx     = (const float*)d_in[2];  // [EMB, HID]
    const float* Wh     = (const float*)d_in[3];  // [HID, HID]
    const float* Wo     = (const float*)d_in[4];  // [HID, VOCAB]
    float* out  = (float*)d_out;                  // [SEQ, BATCH, VOCAB]
    float* Hbuf = (float*)d_ws;                   // SEQ*BATCH*HID f32 = 256 KB

    rnn_recur<<<1, 512, 0, stream>>>(idx, lookup, Wx, Wh, Hbuf);
    logits_lsm<<<NROW / R, T2, 0, stream>>>(Hbuf, Wo, out);
}

// Round 3
// 1138.665 us; speedup vs baseline: 1.1055x; 1.1055x over previous
//
#include <hip/hip_runtime.h>

#define VOCAB 32000
#define EMB 32
#define HID 16
#define SEQ 128
#define BATCH 32
#define NROW (SEQ * BATCH)  // 4096 rows = (t, b) pairs
#define R 8                 // rows per block in logits kernel
#define T2 512              // threads in logits kernel

typedef float f32x4 __attribute__((ext_vector_type(4)));  // clang-native vec
                                                           // (nontemporal ok)

// Kernel 1: embedding gather + 128-step tanh recurrence.
// One block, 512 threads = 32 batch chains x 16 hidden units.
// All per-step dependencies are within a 16-lane group (sX[b][*], sH[b][*]
// touched only by lanes 16b..16b+15, which live in one wave) -> CDNA lockstep
// + in-order LDS make per-step __syncthreads unnecessary. One barrier total.
__global__ __launch_bounds__(512) void rnn_recur(
    const int* __restrict__ idx, const float* __restrict__ lookup,
    const float* __restrict__ Wx, const float* __restrict__ Wh,
    float* __restrict__ Hout)
{
    __shared__ float sWx[EMB][HID];       // 512 f
    __shared__ float sWh[HID][HID];       // 256 f
    __shared__ float sH[BATCH][HID];      // 512 f
    __shared__ float sX[BATCH][EMB + 1];  // padded

    const int tid = threadIdx.x;
    const int b = tid >> 4, j = tid & 15;

    sWx[tid >> 4][tid & 15] = Wx[tid];            // tid spans EMB*HID = 512
    if (tid < HID * HID) sWh[tid >> 4][tid & 15] = Wh[tid];
    sH[b][j] = 1.0f;                              // torch inits H to ones

    const int el = 2 * j;  // thread (b,j) owns X[t][b][2j..2j+1]
    float2 xr = *(const float2*)(lookup + idx[b] * EMB + el);
    __syncthreads();  // weights + sH init visible to all waves (once)

    for (int t = 0; t < SEQ; ++t) {
        sX[b][el] = xr.x;
        sX[b][el + 1] = xr.y;
        if (t + 1 < SEQ) {
            int row = idx[(t + 1) * BATCH + b];
            xr = *(const float2*)(lookup + row * EMB + el);  // prefetch t+1
        }
        float a0 = 0.f, a1 = 0.f, a2 = 0.f, a3 = 0.f;
        #pragma unroll
        for (int e = 0; e < EMB; e += 4) {
            a0 += sX[b][e + 0] * sWx[e + 0][j];
            a1 += sX[b][e + 1] * sWx[e + 1][j];
            a2 += sX[b][e + 2] * sWx[e + 2][j];
            a3 += sX[b][e + 3] * sWx[e + 3][j];
        }
        #pragma unroll
        for (int k = 0; k < HID; k += 4) {
            a0 += sH[b][k + 0] * sWh[k + 0][j];
            a1 += sH[b][k + 1] * sWh[k + 1][j];
            a2 += sH[b][k + 2] * sWh[k + 2][j];
            a3 += sH[b][k + 3] * sWh[k + 3][j];
        }
        float a = (a0 + a1) + (a2 + a3);
        // tanh(a) = 1 - 2/(exp(2a)+1): ~8 inst vs ~30 for tanhf; exact at +-inf
        float e2 = __expf(2.f * a);
        float h = 1.f - 2.f / (e2 + 1.f);
        // lockstep: all 16 lanes of the group finished reading old sH above
        sH[b][j] = h;
        Hout[t * (BATCH * HID) + tid] = h;  // tid == b*HID + j
    }
}

// Kernel 2: logits + log_softmax, two sweeps over vocab, recomputing logits.
// No max subtraction: H is tanh-bounded so |logit| <= ~8, exp safe in f32.
// Output stores are NON-TEMPORAL so the 524 MB write stream does not evict
// the 2 MB Wo from L2 (round-1 failure mode: FETCH 1.97 GB = Wo refetched
// ~1000x because co-resident sweep-2 blocks thrashed L2).
__global__ __launch_bounds__(T2, 4) void logits_lsm(
    const float* __restrict__ H, const float* __restrict__ Wo,
    float* __restrict__ out)
{
    __shared__ __align__(16) float sH[R][HID];
    __shared__ float sWred[8][R];  // one partial per wave
    __shared__ float sLogS[R];

    const int tid = threadIdx.x;
    const int row0 = blockIdx.x * R;

    if (tid < R * HID) sH[tid >> 4][tid & 15] = H[row0 * HID + tid];
    __syncthreads();

    float s[R];
    #pragma unroll
    for (int r = 0; r < R; ++r) s[r] = 0.f;

    // Sweep 1: sum of exp
    for (int v = 4 * tid; v < VOCAB; v += 4 * T2) {
        float4 wo[HID];
        #pragma unroll
        for (int k = 0; k < HID; ++k)
            wo[k] = *(const float4*)(Wo + (size_t)k * VOCAB + v);
        #pragma unroll
        for (int r = 0; r < R; ++r) {
            float l0 = 0, l1 = 0, l2 = 0, l3 = 0;
            #pragma unroll
            for (int k = 0; k < HID; ++k) {
                float h = sH[r][k];
                l0 += h * wo[k].x; l1 += h * wo[k].y;
                l2 += h * wo[k].z; l3 += h * wo[k].w;
            }
            s[r] += __expf(l0) + __expf(l1) + __expf(l2) + __expf(l3);
        }
    }

    // Wave-level shuffle reduce, then tiny LDS combine across the 8 waves
    #pragma unroll
    for (int r = 0; r < R; ++r) {
        #pragma unroll
        for (int off = 32; off > 0; off >>= 1)
            s[r] += __shfl_xor(s[r], off);
    }
    const int wave = tid >> 6, lane = tid & 63;
    if (lane == 0) {
        #pragma unroll
        for (int r = 0; r < R; ++r) sWred[wave][r] = s[r];
    }
    __syncthreads();
    if (tid < R) {
        float tot = 0.f;
        #pragma unroll
        for (int w = 0; w < 8; ++w) tot += sWred[w][tid];
        sLogS[tid] = __logf(tot);
    }
    __syncthreads();

    float lgS[R];
    #pragma unroll
    for (int r = 0; r < R; ++r) lgS[r] = sLogS[r];

    // Sweep 2: recompute logits (Wo L2-resident), nontemporal write
    for (int v = 4 * tid; v < VOCAB; v += 4 * T2) {
        float4 wo[HID];
        #pragma unroll
        for (int k = 0; k < HID; ++k)
            wo[k] = *(const float4*)(Wo + (size_t)k * VOCAB + v);
        #pragma unroll
        for (int r = 0; r < R; ++r) {
            float l0 = 0, l1 = 0, l2 = 0, l3 = 0;
            #pragma unroll
            for (int k = 0; k < HID; ++k) {
                float h = sH[r][k];
                l0 += h * wo[k].x; l1 += h * wo[k].y;
                l2 += h * wo[k].z; l3 += h * wo[k].w;
            }
            f32x4 o;
            o.x = l0 - lgS[r]; o.y = l1 - lgS[r];
            o.z = l2 - lgS[r]; o.w = l3 - lgS[r];
            __builtin_nontemporal_store(
                o, (f32x4*)(out + (size_t)(row0 + r) * VOCAB + v));
        }
    }
}

extern "C" void kernel_launch(void* const* d_in, const int* in_sizes, int n_in,
                              void* d_out, int out_size, void* d_ws, size_t ws_size,
                              hipStream_t stream) {
    const int*   idx    = (const int*)d_in[0];    // [SEQ, BATCH] int32
    const float* lookup = (const float*)d_in[1];  // [VOCAB, EMB]
    const float* Wx     = (const float*)d_in[2];  // [EMB, HID]
    const float* Wh     = (const float*)d_in[3];  // [HID, HID]
    const float* Wo     = (const float*)d_in[4];  // [HID, VOCAB]
    float* out  = (float*)d_out;                  // [SEQ, BATCH, VOCAB]
    float* Hbuf = (float*)d_ws;                   // SEQ*BATCH*HID f32 = 256 KB

    rnn_recur<<<1, 512, 0, stream>>>(idx, lookup, Wx, Wh, Hbuf);
    logits_lsm<<<NROW / R, T2, 0, stream>>>(Hbuf, Wo, out);
}

// Round 4
// 778.947 us; speedup vs baseline: 1.6160x; 1.4618x over previous
//
#include <hip/hip_runtime.h>

#define VOCAB 32000
#define EMB 32
#define HID 16
#define SEQ 128
#define BATCH 32
#define NROW (SEQ * BATCH)  // 4096 rows = (t, b) pairs

typedef float f32x4 __attribute__((ext_vector_type(4)));  // nontemporal-ok vec

// ---------------------------------------------------------------------------
// K1: embedding gather + 128-step tanh recurrence. One block, 512 threads =
// 32 batch chains x 16 hidden units. idx table preloaded to LDS; embedding
// rows prefetched 4 steps deep (independent loads pipeline the ~L2/HBM
// latency that round-3 ate serially, ~900 cyc/step).
// Per-step deps stay inside a 16-lane group -> same-wave LDS ordering, no
// per-step barrier (validated in rounds 1/3).
// ---------------------------------------------------------------------------
__global__ __launch_bounds__(512) void rnn_recur(
    const int* __restrict__ idx, const float* __restrict__ lookup,
    const float* __restrict__ Wx, const float* __restrict__ Wh,
    float* __restrict__ Hout)
{
    __shared__ float sWx[EMB][HID];
    __shared__ float sWh[HID][HID];
    __shared__ float sH[BATCH][HID];
    __shared__ float sX[BATCH][EMB + 1];
    __shared__ int   sIdx[SEQ * BATCH];  // 16 KB

    const int tid = threadIdx.x;
    const int b = tid >> 4, j = tid & 15;

    sWx[tid >> 4][tid & 15] = Wx[tid];
    if (tid < HID * HID) sWh[tid >> 4][tid & 15] = Wh[tid];
    sH[b][j] = 1.0f;  // torch inits H to ones
    #pragma unroll
    for (int i = tid; i < SEQ * BATCH; i += 512) sIdx[i] = idx[i];
    __syncthreads();

    const int el = 2 * j;  // thread (b,j) owns X[t][b][2j..2j+1]
    float2 x0 = *(const float2*)(lookup + sIdx[0 * BATCH + b] * EMB + el);
    float2 x1 = *(const float2*)(lookup + sIdx[1 * BATCH + b] * EMB + el);
    float2 x2 = *(const float2*)(lookup + sIdx[2 * BATCH + b] * EMB + el);
    float2 x3 = *(const float2*)(lookup + sIdx[3 * BATCH + b] * EMB + el);

#define RNN_STEP(XR, T)                                                     \
    {                                                                       \
        sX[b][el] = XR.x; sX[b][el + 1] = XR.y;                             \
        if ((T) + 4 < SEQ) {                                                \
            int row = sIdx[((T) + 4) * BATCH + b];                          \
            XR = *(const float2*)(lookup + row * EMB + el);                 \
        }                                                                   \
        float a0 = 0.f, a1 = 0.f, a2 = 0.f, a3 = 0.f;                       \
        _Pragma("unroll")                                                   \
        for (int e = 0; e < EMB; e += 4) {                                  \
            a0 += sX[b][e + 0] * sWx[e + 0][j];                             \
            a1 += sX[b][e + 1] * sWx[e + 1][j];                             \
            a2 += sX[b][e + 2] * sWx[e + 2][j];                             \
            a3 += sX[b][e + 3] * sWx[e + 3][j];                             \
        }                                                                   \
        _Pragma("unroll")                                                   \
        for (int k = 0; k < HID; k += 4) {                                  \
            a0 += sH[b][k + 0] * sWh[k + 0][j];                             \
            a1 += sH[b][k + 1] * sWh[k + 1][j];                             \
            a2 += sH[b][k + 2] * sWh[k + 2][j];                             \
            a3 += sH[b][k + 3] * sWh[k + 3][j];                             \
        }                                                                   \
        float a = (a0 + a1) + (a2 + a3);                                    \
        float e2 = __expf(2.f * a);      /* tanh = 1 - 2/(e^{2a}+1) */      \
        float h = 1.f - 2.f / (e2 + 1.f);                                   \
        sH[b][j] = h;                                                       \
        Hout[(T) * (BATCH * HID) + tid] = h;                                \
    }

    for (int t = 0; t < SEQ; t += 4) {
        RNN_STEP(x0, t + 0)
        RNN_STEP(x1, t + 1)
        RNN_STEP(x2, t + 2)
        RNN_STEP(x3, t + 3)
    }
#undef RNN_STEP
}

// ---------------------------------------------------------------------------
// K2: partial exp-sums. Grid = 8 vocab slices (XCD-affine: vtile = bid & 7,
// one 256 KB Wo slice per XCD's L2) x 256 row tiles (R2=16 rows). No output
// write stream in this kernel -> slice stays L2-hot even if reuse is
// imperfect the fetch is bounded at 2048 blocks x 256 KB = 512 MB.
// Writes partials P[vtile][row] (each written once -> deterministic).
// No max subtraction: H tanh-bounded => |logit| <= ~1.5, exp safe in f32.
// ---------------------------------------------------------------------------
#define R2 16
#define VS2 4000  // vocab slice width for K2

__global__ __launch_bounds__(512, 4) void sum_exp_partial(
    const float* __restrict__ H, const float* __restrict__ Wo,
    float* __restrict__ P)
{
    __shared__ __align__(16) float sH[R2][HID];
    __shared__ float sWred[8][R2];

    const int tid = threadIdx.x;
    const int vtile = blockIdx.x & 7;
    const int row0 = (blockIdx.x >> 3) * R2;
    const int vbase = vtile * VS2;

    if (tid < R2 * HID) sH[tid >> 4][tid & 15] = H[row0 * HID + tid];
    __syncthreads();

    float s[R2];
    #pragma unroll
    for (int r = 0; r < R2; ++r) s[r] = 0.f;

    for (int v = vbase + 4 * tid; v < vbase + VS2; v += 4 * 512) {
        float4 wo[HID];
        #pragma unroll
        for (int k = 0; k < HID; ++k)
            wo[k] = *(const float4*)(Wo + (size_t)k * VOCAB + v);
        #pragma unroll
        for (int r = 0; r < R2; ++r) {
            float l0 = 0, l1 = 0, l2 = 0, l3 = 0;
            #pragma unroll
            for (int k = 0; k < HID; ++k) {
                float h = sH[r][k];
                l0 += h * wo[k].x; l1 += h * wo[k].y;
                l2 += h * wo[k].z; l3 += h * wo[k].w;
            }
            s[r] += __expf(l0) + __expf(l1) + __expf(l2) + __expf(l3);
        }
    }

    #pragma unroll
    for (int r = 0; r < R2; ++r) {
        #pragma unroll
        for (int off = 32; off > 0; off >>= 1)
            s[r] += __shfl_xor(s[r], off);
    }
    const int wave = tid >> 6, lane = tid & 63;
    if (lane == 0) {
        #pragma unroll
        for (int r = 0; r < R2; ++r) sWred[wave][r] = s[r];
    }
    __syncthreads();
    if (tid < R2) {
        float tot = 0.f;
        #pragma unroll
        for (int w = 0; w < 8; ++w) tot += sWred[w][tid];
        P[(size_t)vtile * NROW + row0 + tid] = tot;
    }
}

// K2b: logS[row] = log( sum_v P[v][row] )
__global__ __launch_bounds__(512) void reduce_logS(
    const float* __restrict__ P, float* __restrict__ logS)
{
    int i = blockIdx.x * 512 + threadIdx.x;  // 4096 threads
    float tot = 0.f;
    #pragma unroll
    for (int v = 0; v < 8; ++v) tot += P[(size_t)v * NROW + i];
    logS[i] = __logf(tot);
}

// ---------------------------------------------------------------------------
// K3: output pass. Thread owns 4 vocab columns; Wo slice lives in REGISTERS
// (16 x float4 = 64 VGPR) for the whole block -> Wo traffic is one load per
// block (64 MB total worst case) and completely immune to L2 eviction by the
// 524 MB write stream. Block = 2000-col slice x 128 rows; per row: broadcast
// H row from LDS, 64 FMA, NT store of float4.
// ---------------------------------------------------------------------------
#define R3 128   // rows per block
#define VS3 2000 // vocab cols per block (500 active threads x 4)

__global__ __launch_bounds__(512, 4) void write_logits(
    const float* __restrict__ H, const float* __restrict__ Wo,
    const float* __restrict__ logS, float* __restrict__ out)
{
    __shared__ __align__(16) float sH[R3 * HID];  // 8 KB
    __shared__ float sLogS[R3];

    const int tid = threadIdx.x;
    const int vtile = blockIdx.x & 15;         // 16 x 2000 = 32000
    const int row0 = (blockIdx.x >> 4) * R3;   // 32 row tiles
    const int vbase = vtile * VS3;

    *(float4*)(sH + 4 * tid) = *(const float4*)(H + row0 * HID + 4 * tid);
    if (tid < R3) sLogS[tid] = logS[row0 + tid];
    __syncthreads();

    if (tid >= VS3 / 4) return;  // threads 500..511 done (no later barriers)

    const int v = vbase + 4 * tid;
    float4 wo[HID];
    #pragma unroll
    for (int k = 0; k < HID; ++k)
        wo[k] = *(const float4*)(Wo + (size_t)k * VOCAB + v);

    float* orow = out + (size_t)row0 * VOCAB + v;
    for (int r = 0; r < R3; ++r) {
        float l0 = 0, l1 = 0, l2 = 0, l3 = 0;
        #pragma unroll
        for (int k = 0; k < HID; ++k) {
            float h = sH[r * HID + k];  // same addr all lanes: LDS broadcast
            l0 += h * wo[k].x; l1 += h * wo[k].y;
            l2 += h * wo[k].z; l3 += h * wo[k].w;
        }
        float ls = sLogS[r];
        f32x4 o;
        o.x = l0 - ls; o.y = l1 - ls; o.z = l2 - ls; o.w = l3 - ls;
        __builtin_nontemporal_store(o, (f32x4*)orow);
        orow += VOCAB;
    }
}

extern "C" void kernel_launch(void* const* d_in, const int* in_sizes, int n_in,
                              void* d_out, int out_size, void* d_ws, size_t ws_size,
                              hipStream_t stream) {
    const int*   idx    = (const int*)d_in[0];    // [SEQ, BATCH] int32
    const float* lookup = (const float*)d_in[1];  // [VOCAB, EMB]
    const float* Wx     = (const float*)d_in[2];  // [EMB, HID]
    const float* Wh     = (const float*)d_in[3];  // [HID, HID]
    const float* Wo     = (const float*)d_in[4];  // [HID, VOCAB]
    float* out = (float*)d_out;                   // [SEQ, BATCH, VOCAB]

    // ws layout: H (256 KB) | P partials 8x4096 (128 KB) | logS (16 KB)
    float* Hbuf = (float*)d_ws;
    float* P    = Hbuf + NROW * HID;
    float* logS = P + 8 * NROW;

    rnn_recur<<<1, 512, 0, stream>>>(idx, lookup, Wx, Wh, Hbuf);
    sum_exp_partial<<<8 * (NROW / R2), 512, 0, stream>>>(Hbuf, Wo, P);
    reduce_logS<<<NROW / 512, 512, 0, stream>>>(P, logS);
    write_logits<<<16 * (NROW / R3), 512, 0, stream>>>(Hbuf, Wo, logS, out);
}

// Round 5
// 278.095 us; speedup vs baseline: 4.5264x; 2.8010x over previous
//
#include <hip/hip_runtime.h>

#define VOCAB 32000
#define EMB 32
#define HID 16
#define SEQ 128
#define BATCH 32
#define NROW (SEQ * BATCH)  // 4096 rows = (t, b) pairs

typedef float f32x4 __attribute__((ext_vector_type(4)));  // nontemporal-ok vec

// ---------------------------------------------------------------------------
// K1: embedding gather + 128-step tanh recurrence. One block, 512 threads =
// 32 batch chains x 16 hidden units. idx in LDS; embeddings prefetched 4 deep.
// Per-step deps stay inside a 16-lane group -> same-wave LDS ordering, no
// per-step barrier (validated rounds 1/3/4).
// ---------------------------------------------------------------------------
__global__ __launch_bounds__(512) void rnn_recur(
    const int* __restrict__ idx, const float* __restrict__ lookup,
    const float* __restrict__ Wx, const float* __restrict__ Wh,
    float* __restrict__ Hout)
{
    __shared__ float sWx[EMB][HID];
    __shared__ float sWh[HID][HID];
    __shared__ float sH[BATCH][HID];
    __shared__ float sX[BATCH][EMB + 1];
    __shared__ int   sIdx[SEQ * BATCH];  // 16 KB

    const int tid = threadIdx.x;
    const int b = tid >> 4, j = tid & 15;

    sWx[tid >> 4][tid & 15] = Wx[tid];
    if (tid < HID * HID) sWh[tid >> 4][tid & 15] = Wh[tid];
    sH[b][j] = 1.0f;  // torch inits H to ones
    #pragma unroll
    for (int i = tid; i < SEQ * BATCH; i += 512) sIdx[i] = idx[i];
    __syncthreads();

    const int el = 2 * j;  // thread (b,j) owns X[t][b][2j..2j+1]
    float2 x0 = *(const float2*)(lookup + sIdx[0 * BATCH + b] * EMB + el);
    float2 x1 = *(const float2*)(lookup + sIdx[1 * BATCH + b] * EMB + el);
    float2 x2 = *(const float2*)(lookup + sIdx[2 * BATCH + b] * EMB + el);
    float2 x3 = *(const float2*)(lookup + sIdx[3 * BATCH + b] * EMB + el);

#define RNN_STEP(XR, T)                                                     \
    {                                                                       \
        sX[b][el] = XR.x; sX[b][el + 1] = XR.y;                             \
        if ((T) + 4 < SEQ) {                                                \
            int row = sIdx[((T) + 4) * BATCH + b];                          \
            XR = *(const float2*)(lookup + row * EMB + el);                 \
        }                                                                   \
        float a0 = 0.f, a1 = 0.f, a2 = 0.f, a3 = 0.f;                       \
        _Pragma("unroll")                                                   \
        for (int e = 0; e < EMB; e += 4) {                                  \
            a0 += sX[b][e + 0] * sWx[e + 0][j];                             \
            a1 += sX[b][e + 1] * sWx[e + 1][j];                             \
            a2 += sX[b][e + 2] * sWx[e + 2][j];                             \
            a3 += sX[b][e + 3] * sWx[e + 3][j];                             \
        }                                                                   \
        _Pragma("unroll")                                                   \
        for (int k = 0; k < HID; k += 4) {                                  \
            a0 += sH[b][k + 0] * sWh[k + 0][j];                             \
            a1 += sH[b][k + 1] * sWh[k + 1][j];                             \
            a2 += sH[b][k + 2] * sWh[k + 2][j];                             \
            a3 += sH[b][k + 3] * sWh[k + 3][j];                             \
        }                                                                   \
        float a = (a0 + a1) + (a2 + a3);                                    \
        float e2 = __expf(2.f * a);      /* tanh = 1 - 2/(e^{2a}+1) */      \
        float h = 1.f - 2.f / (e2 + 1.f);                                   \
        sH[b][j] = h;                                                       \
        Hout[(T) * (BATCH * HID) + tid] = h;                                \
    }

    for (int t = 0; t < SEQ; t += 4) {
        RNN_STEP(x0, t + 0)
        RNN_STEP(x1, t + 1)
        RNN_STEP(x2, t + 2)
        RNN_STEP(x3, t + 3)
    }
#undef RNN_STEP
}

// ---------------------------------------------------------------------------
// K2 (v2): partial exp-sums with Wo slice in REGISTERS (round-4 lesson: L2
// reuse of Wo is unwinnable against the 524 MB/replay output drain; only
// registers are safe — write_logits proved it). Block = 2000-col slice
// (16 float4 = 64 VGPR, one HBM load) x 128 rows. Per row: 4-col exp-sum,
// wave shfl reduce, per-wave LDS slot (no barrier in the loop), then one
// barrier + cross-wave sum -> P[vtile][row]. Deterministic (each P written
// once). No max subtraction: H tanh-bounded => exp safe in f32.
// ---------------------------------------------------------------------------
#define RV 128   // rows per block
#define VSK 2000 // vocab cols per block slice (500 active threads x 4)

__global__ __launch_bounds__(512, 4) void sum_exp_partial(
    const float* __restrict__ H, const float* __restrict__ Wo,
    float* __restrict__ P)
{
    __shared__ __align__(16) float sH[RV * HID];  // 8 KB
    __shared__ float part[8][RV];                 // 4 KB, per-wave partials

    const int tid = threadIdx.x;
    const int wave = tid >> 6;
    const int vtile = blockIdx.x & 15;         // 16 x 2000 = 32000
    const int row0 = (blockIdx.x >> 4) * RV;   // 32 row chunks

    *(float4*)(sH + 4 * tid) = *(const float4*)(H + row0 * HID + 4 * tid);
    __syncthreads();

    const bool active = (4 * tid < VSK);
    const int v = vtile * VSK + (active ? 4 * tid : 0);  // clamp: no OOB
    float4 wo[HID];
    #pragma unroll
    for (int k = 0; k < HID; ++k)
        wo[k] = *(const float4*)(Wo + (size_t)k * VOCAB + v);
    const float amask = active ? 1.f : 0.f;

    for (int r = 0; r < RV; ++r) {
        float l0 = 0, l1 = 0, l2 = 0, l3 = 0;
        #pragma unroll
        for (int k = 0; k < HID; ++k) {
            float h = sH[r * HID + k];  // uniform addr: LDS broadcast
            l0 += h * wo[k].x; l1 += h * wo[k].y;
            l2 += h * wo[k].z; l3 += h * wo[k].w;
        }
        float s = amask * ((__expf(l0) + __expf(l1)) +
                           (__expf(l2) + __expf(l3)));
        #pragma unroll
        for (int off = 32; off > 0; off >>= 1)
            s += __shfl_xor(s, off);
        if ((tid & 63) == 0) part[wave][r] = s;  // own slot: no barrier
    }
    __syncthreads();
    if (tid < RV) {
        float tot = 0.f;
        #pragma unroll
        for (int w = 0; w < 8; ++w) tot += part[w][tid];
        P[(size_t)vtile * NROW + row0 + tid] = tot;
    }
}

// K2b: logS[row] = log( sum_v P[v][row] ), 16 partials
__global__ __launch_bounds__(512) void reduce_logS(
    const float* __restrict__ P, float* __restrict__ logS)
{
    int i = blockIdx.x * 512 + threadIdx.x;  // 4096 threads
    float tot = 0.f;
    #pragma unroll
    for (int v = 0; v < 16; ++v) tot += P[(size_t)v * NROW + i];
    logS[i] = __logf(tot);
}

// ---------------------------------------------------------------------------
// K3: output pass, Wo slice in registers (unchanged from round 4 — it was
// the part that worked). Block = 2000-col slice x 128 rows, NT stores.
// ---------------------------------------------------------------------------
__global__ __launch_bounds__(512, 4) void write_logits(
    const float* __restrict__ H, const float* __restrict__ Wo,
    const float* __restrict__ logS, float* __restrict__ out)
{
    __shared__ __align__(16) float sH[RV * HID];  // 8 KB
    __shared__ float sLogS[RV];

    const int tid = threadIdx.x;
    const int vtile = blockIdx.x & 15;
    const int row0 = (blockIdx.x >> 4) * RV;
    const int vbase = vtile * VSK;

    *(float4*)(sH + 4 * tid) = *(const float4*)(H + row0 * HID + 4 * tid);
    if (tid < RV) sLogS[tid] = logS[row0 + tid];
    __syncthreads();

    if (tid >= VSK / 4) return;  // threads 500..511 done (no later barriers)

    const int v = vbase + 4 * tid;
    float4 wo[HID];
    #pragma unroll
    for (int k = 0; k < HID; ++k)
        wo[k] = *(const float4*)(Wo + (size_t)k * VOCAB + v);

    float* orow = out + (size_t)row0 * VOCAB + v;
    for (int r = 0; r < RV; ++r) {
        float l0 = 0, l1 = 0, l2 = 0, l3 = 0;
        #pragma unroll
        for (int k = 0; k < HID; ++k) {
            float h = sH[r * HID + k];  // uniform addr: LDS broadcast
            l0 += h * wo[k].x; l1 += h * wo[k].y;
            l2 += h * wo[k].z; l3 += h * wo[k].w;
        }
        float ls = sLogS[r];
        f32x4 o;
        o.x = l0 - ls; o.y = l1 - ls; o.z = l2 - ls; o.w = l3 - ls;
        __builtin_nontemporal_store(o, (f32x4*)orow);
        orow += VOCAB;
    }
}

extern "C" void kernel_launch(void* const* d_in, const int* in_sizes, int n_in,
                              void* d_out, int out_size, void* d_ws, size_t ws_size,
                              hipStream_t stream) {
    const int*   idx    = (const int*)d_in[0];    // [SEQ, BATCH] int32
    const float* lookup = (const float*)d_in[1];  // [VOCAB, EMB]
    const float* Wx     = (const float*)d_in[2];  // [EMB, HID]
    const float* Wh     = (const float*)d_in[3];  // [HID, HID]
    const float* Wo     = (const float*)d_in[4];  // [HID, VOCAB]
    float* out = (float*)d_out;                   // [SEQ, BATCH, VOCAB]

    // ws layout: H (256 KB) | P partials 16x4096 (256 KB) | logS (16 KB)
    float* Hbuf = (float*)d_ws;
    float* P    = Hbuf + NROW * HID;
    float* logS = P + 16 * NROW;

    rnn_recur<<<1, 512, 0, stream>>>(idx, lookup, Wx, Wh, Hbuf);
    sum_exp_partial<<<16 * (NROW / RV), 512, 0, stream>>>(Hbuf, Wo, P);
    reduce_logS<<<NROW / 512, 512, 0, stream>>>(P, logS);
    write_logits<<<16 * (NROW / RV), 512, 0, stream>>>(Hbuf, Wo, logS, out);
}